// Round 5
// baseline (12208.173 us; speedup 1.0000x reference)
//
#include <hip/hip_runtime.h>

// PositionCloser round 5: barrierless, 1 sequence per wave (1024 waves = 1/SIMD).
// All of W_hh^T (16 f16 B-frag tiles) + a W_out z-tile live in registers; MFMA
// reads them directly. Per step: h -> f16 pairs -> 8 ds_bpermute build the
// (replicated-row) A operand; 34 MFMA produce all 256 gate preacts + z; 16
// bpermute + 12 cndmask redistribute D row0 to lane=hid; gates elementwise;
// loss is lag-1 with z coming out of the MFMA pipe (z_t = wo.h_t emerges when
// h_t is used as the A operand of step t+1). Zero LDS arrays, zero barriers.

#define CH  128
#define HID 64

typedef __fp16 f16x8 __attribute__((ext_vector_type(8)));
typedef __fp16 f16x2 __attribute__((ext_vector_type(2)));
typedef float  f32x4 __attribute__((ext_vector_type(4)));
typedef int    i32x4 __attribute__((ext_vector_type(4)));

#define MFMA16(a, b, c) __builtin_amdgcn_mfma_f32_16x16x32_f16((a), (b), (c), 0, 0, 0)

__device__ __forceinline__ float rlf(float v, int l) {
  return __builtin_bit_cast(float, __builtin_amdgcn_readlane(__builtin_bit_cast(int, v), l));
}
__device__ __forceinline__ int packh(float a, float b) {
  f16x2 v = __builtin_amdgcn_cvt_pkrtz(a, b);
  return __builtin_bit_cast(int, v);
}
__device__ __forceinline__ int bperm(int byteaddr, int src) {
  return __builtin_amdgcn_ds_bpermute(byteaddr, src);
}
__device__ __forceinline__ float bpermf(int byteaddr, float src) {
  return __builtin_bit_cast(float,
      __builtin_amdgcn_ds_bpermute(byteaddr, __builtin_bit_cast(int, src)));
}
__device__ __forceinline__ float frcp(float x) { return __builtin_amdgcn_rcpf(x); }
__device__ __forceinline__ float sigm(float x) { return frcp(1.0f + __expf(-x)); }
__device__ __forceinline__ float tanh_(float x) {
  float e = __expf(2.0f * x);
  return 1.0f - 2.0f * frcp(e + 1.0f);
}

__global__ __launch_bounds__(256, 1)
void pc_lstm_kernel(const int* __restrict__ inds,
                    const float* __restrict__ p,
                    const float* __restrict__ ls_probs,
                    const float* __restrict__ open_probs,
                    const int* __restrict__ open_slices,
                    const float* __restrict__ open_hx,
                    const float* __restrict__ W_ih,
                    const float* __restrict__ W_hh,
                    const float* __restrict__ b_ih,
                    const float* __restrict__ b_hh,
                    const float* __restrict__ W_out,
                    const float* __restrict__ b_out,
                    const int* __restrict__ n_chunks_p,
                    float* __restrict__ out)
{
  const int lane = threadIdx.x & 63;
  const int w    = threadIdx.x >> 6;
  const int s    = blockIdx.x * 4 + w;     // sequence id, 0..1023
  const int q    = lane >> 4;
  const int lm   = lane & 15;
  const int n_chunks = n_chunks_p[0];

  // ---- B fragments: W_hh^T tiles, f16. B[k][n]: n=lm -> W row g*64+16cb+lm,
  // k = 32*kh + 8*q + j -> W col. 32 frags = 128 VGPRs.
  f16x8 Bf[4][4][2];
#pragma unroll
  for (int g = 0; g < 4; ++g)
#pragma unroll
    for (int cb = 0; cb < 4; ++cb)
#pragma unroll
      for (int kh = 0; kh < 2; ++kh) {
        const float* src = W_hh + (g * HID + 16 * cb + lm) * HID + 32 * kh + 8 * q;
        f16x8 b;
#pragma unroll
        for (int j = 0; j < 8; ++j) b[j] = (__fp16)src[j];
        Bf[g][cb][kh] = b;
      }
  // z-tile: column 0 = W_out, rest 0 -> D[0][0] = wo . h
  f16x8 Bz[2];
#pragma unroll
  for (int kh = 0; kh < 2; ++kh) {
    f16x8 b;
#pragma unroll
    for (int j = 0; j < 8; ++j)
      b[j] = (lm == 0) ? (__fp16)W_out[32 * kh + 8 * q + j] : (__fp16)0.0f;
    Bz[kh] = b;
  }

  // ---- per-lane (lane = hid) gate constants
  float wxa[4], wxb[4], bb[4];
#pragma unroll
  for (int g = 0; g < 4; ++g) {
    const int row = g * HID + lane;
    wxa[g] = W_ih[2 * row];
    wxb[g] = W_ih[2 * row + 1];
    bb[g]  = b_ih[row] + b_hh[row];
  }
  const float wo   = W_out[lane];
  const float bout = b_out[0];

  // ---- per-sequence state / loss constants
  float h = open_hx[(s * 2 + 0) * HID + lane];
  float c = open_hx[(s * 2 + 1) * HID + lane];
  const int   os   = open_slices[s];
  const float OL   = __logf(p[2 * os]) + __logf(p[2 * os + 1]);
  const float coef = open_probs[s] * (2.0f * ls_probs[s] - 1.0f);
  const int   tbase = inds[s >> 4] + (s & 15);

  // bpermute byte addresses (loop-invariant)
  int aadr0[4], aadr1[4];
#pragma unroll
  for (int m = 0; m < 4; ++m) {
    aadr0[m] = 8 * (4 * q + m);        // h pair (8q+2m, 8q+2m+1), K-half 0
    aadr1[m] = 8 * (16 + 4 * q + m);   // K-half 1
  }
  const int dadr = 4 * lm;             // D redistribute: pull from lane lm

  float Sd = 1.0f, Qd = 1.0f, lsum = 0.0f, psum = 0.0f;
  float Lcarry = 0.0f;
  float LBprev = 0.0f;                 // per-lane LB of previous chunk

  const float2* p2 = (const float2*)p;
  float2 curA = p2[tbase + lane];          // t = lane
  float2 curB = p2[tbase + HID + lane];    // t = 64 + lane
  float2 nxtA = curA, nxtB = curB;

  for (int off = 0; off < n_chunks; ++off) {
    if (off) { Lcarry = rlf(LBprev, 63); curA = nxtA; curB = nxtB; }
    const float LA = __logf(curA.x) + __logf(curA.y);
    const float LB = __logf(curB.x) + __logf(curB.y);
    const float px0 = rlf(curA.x, 0);
    const float px1 = rlf(curA.y, 0);
    if (off + 1 < n_chunks) {
      const int nb = tbase + (off + 1) * CH;
      nxtA = p2[nb + lane];
      nxtB = p2[nb + HID + lane];
    }

#pragma unroll 1
    for (int tt = 0; tt < CH; ++tt) {
      // ---- A operand from current h (rows replicated; addr independent of lm)
      const int hp = packh(h, __shfl_xor(h, 1, 64));   // valid at even lanes
      i32x4 t0, t1;
#pragma unroll
      for (int m = 0; m < 4; ++m) {
        t0[m] = bperm(aadr0[m], hp);
        t1[m] = bperm(aadr1[m], hp);
      }
      const f16x8 a0 = __builtin_bit_cast(f16x8, t0);
      const f16x8 a1 = __builtin_bit_cast(f16x8, t1);

      const f32x4 zero4 = {0.0f, 0.0f, 0.0f, 0.0f};
      // z of the ENTERING h -> prob of the previous step (lag-1)
      f32x4 Cz = MFMA16(a0, Bz[0], zero4);
      Cz = MFMA16(a1, Bz[1], Cz);

      // ---- 32 MFMA: 4 gates x 4 col-blocks; redistribute D row0 in-wave
      float pre[4];
#pragma unroll
      for (int g = 0; g < 4; ++g) {
        f32x4 C0 = MFMA16(a0, Bf[g][0][0], zero4); C0 = MFMA16(a1, Bf[g][0][1], C0);
        f32x4 C1 = MFMA16(a0, Bf[g][1][0], zero4); C1 = MFMA16(a1, Bf[g][1][1], C1);
        f32x4 C2 = MFMA16(a0, Bf[g][2][0], zero4); C2 = MFMA16(a1, Bf[g][2][1], C2);
        f32x4 C3 = MFMA16(a0, Bf[g][3][0], zero4); C3 = MFMA16(a1, Bf[g][3][1], C3);
        const float r0 = bpermf(dadr, C0[0]);
        const float r1 = bpermf(dadr, C1[0]);
        const float r2 = bpermf(dadr, C2[0]);
        const float r3 = bpermf(dadr, C3[0]);
        pre[g] = (q == 0) ? r0 : (q == 1) ? r1 : (q == 2) ? r2 : r3;
      }

      // ---- lagged loss (wave-uniform; overlaps MFMA latency)
      const float zprev = rlf(Cz[0], 0);
      if (off | tt) {
        const int ltt = (tt == 0) ? (CH - 1) : (tt - 1);
        const float Lt = (tt == 0) ? Lcarry
                       : (ltt < 64) ? rlf(LA, ltt) : rlf(LB, ltt - 64);
        const float pr = sigm(zprev + bout);
        if (ltt == 0) Qd = 1.0f;
        const float T  = (ltt == 0) ? 1.0f : Sd * Qd;   // chunk t=0 undiscounted
        const float pn = pr * T;
        lsum = fmaf(pn, Lt, lsum);
        psum += pn;
        if (ltt == CH - 1) Sd *= Qd;                    // carry excludes (1-p_last)
        Qd *= (1.0f - pr);
      }

      // ---- input contribution + gates (lane = hid)
      const float sp0 = (tt < 64) ? rlf(curA.x, tt) : rlf(curB.x, tt & 63);
      const float sp1 = (tt < 64) ? rlf(curA.y, tt) : rlf(curB.y, tt & 63);
      const float x0 = sp0 - px0;
      const float x1 = sp1 - px1;
#pragma unroll
      for (int g = 0; g < 4; ++g)
        pre[g] = fmaf(x1, wxb[g], fmaf(x0, wxa[g], pre[g] + bb[g]));

      const float ig = sigm(pre[0]);
      const float fg = sigm(pre[1]);
      const float gg = tanh_(pre[2]);
      const float og = sigm(pre[3]);
      c = fmaf(fg, c, ig * gg);
      h = og * tanh_(c);
    }
    LBprev = LB;
  }

  // ---- drain the final step's prob (one-time f32 shuffle reduce)
  {
    float zp = h * wo;
#pragma unroll
    for (int m = 32; m > 0; m >>= 1) zp += __shfl_xor(zp, m, 64);
    const float pr = sigm(zp + bout);
    const float pn = pr * Sd * Qd;                      // ltt = 127 != 0
    lsum = fmaf(pn, rlf(LBprev, 63), lsum);
    psum += pn;
  }

  if (lane == 0) atomicAdd(out, coef * (lsum - OL * psum));
}

extern "C" void kernel_launch(void* const* d_in, const int* in_sizes, int n_in,
                              void* d_out, int out_size, void* d_ws, size_t ws_size,
                              hipStream_t stream) {
  (void)hipMemsetAsync(d_out, 0, sizeof(float), stream);

  pc_lstm_kernel<<<dim3(256), dim3(256), 0, stream>>>(
      (const int*)d_in[0],    // inds
      (const float*)d_in[1],  // p
      (const float*)d_in[2],  // ls_probs
      (const float*)d_in[3],  // open_probs
      (const int*)d_in[4],    // open_slices
      (const float*)d_in[5],  // open_hx
      (const float*)d_in[6],  // W_ih
      (const float*)d_in[7],  // W_hh
      (const float*)d_in[8],  // b_ih
      (const float*)d_in[9],  // b_hh
      (const float*)d_in[10], // W_out
      (const float*)d_in[11], // b_out
      (const int*)d_in[12],   // n_chunks
      (float*)d_out);
}

// Round 7
// 10747.496 us; speedup vs baseline: 1.1359x; 1.1359x over previous
//
#include <hip/hip_runtime.h>

// PositionCloser round 7 (= round 6 with DPP helper templated on the constant
// ctrl/row-mask — __builtin_amdgcn_update_dpp requires ICE arguments).
// R3 fdot2 structure, 1 seq/wave, 1024 waves = 1/SIMD. The 128 packed-f16x2
// W_hh words are FORCED into architectural VGPRs via empty asm "+v" pins
// inside the t-loop (R1/R3 evidence: allocator parks big register arrays in
// AGPRs -> one v_accvgpr_read per use, ~2x instr tax). Neighbor pack via DPP
// quad_perm, z-reduce via DPP row_shr/bcast chain, loss lag-1 so the z chain
// is off the h-recurrence critical path.

#define CH  128
#define HID 64

typedef __fp16 f16x2 __attribute__((ext_vector_type(2)));

__device__ __forceinline__ float rlf(float v, int l) {
  return __builtin_bit_cast(float, __builtin_amdgcn_readlane(__builtin_bit_cast(int, v), l));
}
__device__ __forceinline__ int rli(int v, int l) { return __builtin_amdgcn_readlane(v, l); }
__device__ __forceinline__ int packh(float a, float b) {
  return __builtin_bit_cast(int, __builtin_amdgcn_cvt_pkrtz(a, b));
}
__device__ __forceinline__ f16x2 h2(int v) { return __builtin_bit_cast(f16x2, v); }
__device__ __forceinline__ float frcp(float x) { return __builtin_amdgcn_rcpf(x); }
__device__ __forceinline__ float sigm(float x) { return frcp(1.0f + __expf(-x)); }
__device__ __forceinline__ float tanh_(float x) {
  float e = __expf(2.0f * x);
  return 1.0f - 2.0f * frcp(e + 1.0f);
}
// v += dpp(v); masked-out rows add 0 (old=0, bound_ctrl=true)
template <int CTRL, int RMASK>
__device__ __forceinline__ float dpp_add(float v) {
  int x = __builtin_amdgcn_update_dpp(0, __builtin_bit_cast(int, v), CTRL, RMASK, 0xF, true);
  return v + __builtin_bit_cast(float, x);
}
__device__ __forceinline__ float dpp_xor1(float v) {  // quad_perm [1,0,3,2]
  int x = __builtin_amdgcn_update_dpp(0, __builtin_bit_cast(int, v), 0xB1, 0xF, 0xF, true);
  return __builtin_bit_cast(float, x);
}
// full-wave sum -> valid in lane 63
__device__ __forceinline__ float dpp_wave_sum(float v) {
  v = dpp_add<0x111, 0xF>(v);   // row_shr:1
  v = dpp_add<0x112, 0xF>(v);   // row_shr:2
  v = dpp_add<0x114, 0xF>(v);   // row_shr:4
  v = dpp_add<0x118, 0xF>(v);   // row_shr:8  -> lane15 of each row = row sum
  v = dpp_add<0x142, 0xA>(v);   // row_bcast:15 -> lane31/63 accumulate
  v = dpp_add<0x143, 0xC>(v);   // row_bcast:31 -> lane63 = total
  return v;
}

#define PIN32(W) asm volatile("" : \
  "+v"(W[0]),"+v"(W[1]),"+v"(W[2]),"+v"(W[3]),"+v"(W[4]),"+v"(W[5]),"+v"(W[6]),"+v"(W[7]), \
  "+v"(W[8]),"+v"(W[9]),"+v"(W[10]),"+v"(W[11]),"+v"(W[12]),"+v"(W[13]),"+v"(W[14]),"+v"(W[15]), \
  "+v"(W[16]),"+v"(W[17]),"+v"(W[18]),"+v"(W[19]),"+v"(W[20]),"+v"(W[21]),"+v"(W[22]),"+v"(W[23]), \
  "+v"(W[24]),"+v"(W[25]),"+v"(W[26]),"+v"(W[27]),"+v"(W[28]),"+v"(W[29]),"+v"(W[30]),"+v"(W[31]))

__global__ __launch_bounds__(64, 1)
void pc_lstm_kernel(const int* __restrict__ inds,
                    const float* __restrict__ p,
                    const float* __restrict__ ls_probs,
                    const float* __restrict__ open_probs,
                    const int* __restrict__ open_slices,
                    const float* __restrict__ open_hx,
                    const float* __restrict__ W_ih,
                    const float* __restrict__ W_hh,
                    const float* __restrict__ b_ih,
                    const float* __restrict__ b_hh,
                    const float* __restrict__ W_out,
                    const float* __restrict__ b_out,
                    const int* __restrict__ n_chunks_p,
                    float* __restrict__ out)
{
  const int lane = threadIdx.x;      // 0..63
  const int s    = blockIdx.x;       // 0..1023
  const int n_chunks = n_chunks_p[0];

  // ---- recurrent weights: lane owns gate rows g*64+lane; packed f16x2, 128 regs
  int W0[HID / 2], W1[HID / 2], W2[HID / 2], W3[HID / 2];
  {
    const float2* r0 = (const float2*)(W_hh + (0 * HID + lane) * HID);
    const float2* r1 = (const float2*)(W_hh + (1 * HID + lane) * HID);
    const float2* r2 = (const float2*)(W_hh + (2 * HID + lane) * HID);
    const float2* r3 = (const float2*)(W_hh + (3 * HID + lane) * HID);
#pragma unroll
    for (int j = 0; j < HID / 2; ++j) {
      float2 v0 = r0[j], v1 = r1[j], v2 = r2[j], v3 = r3[j];
      W0[j] = packh(v0.x, v0.y);
      W1[j] = packh(v1.x, v1.y);
      W2[j] = packh(v2.x, v2.y);
      W3[j] = packh(v3.x, v3.y);
    }
  }

  // per-lane input weights + fused bias
  float wxa[4], wxb[4], bb[4];
#pragma unroll
  for (int g = 0; g < 4; ++g) {
    const int r = g * HID + lane;
    wxa[g] = W_ih[2 * r];
    wxb[g] = W_ih[2 * r + 1];
    bb[g]  = b_ih[r] + b_hh[r];
  }
  const float wo   = W_out[lane];
  const float bout = b_out[0];

  // ---- per-sequence state / loss constants
  float h = open_hx[(s * 2 + 0) * HID + lane];
  float c = open_hx[(s * 2 + 1) * HID + lane];
  const int   os    = open_slices[s];
  const float OL    = __logf(p[2 * os]) + __logf(p[2 * os + 1]);
  const float coef  = open_probs[s] * (2.0f * ls_probs[s] - 1.0f);
  const int   tbase = inds[s >> 4] + (s & 15);

  float Sd = 1.0f, Qd = 1.0f, lsum = 0.0f, psum = 0.0f;
  float Lcarry = 0.0f, LBprev = 0.0f;

  const float2* p2 = (const float2*)p;
  float2 curA = p2[tbase + lane];          // t = lane
  float2 curB = p2[tbase + HID + lane];    // t = 64 + lane
  float2 nxtA = curA, nxtB = curB;

  for (int off = 0; off < n_chunks; ++off) {
    if (off) { Lcarry = rlf(LBprev, 63); curA = nxtA; curB = nxtB; }
    const float LA = __logf(curA.x) + __logf(curA.y);
    const float LB = __logf(curB.x) + __logf(curB.y);
    const float px0 = rlf(curA.x, 0);
    const float px1 = rlf(curA.y, 0);
    if (off + 1 < n_chunks) {
      const int nb = tbase + (off + 1) * CH;
      nxtA = p2[nb + lane];
      nxtB = p2[nb + HID + lane];
    }

#pragma unroll 1
    for (int tt = 0; tt < CH; ++tt) {
      // keep the weight words resident in architectural VGPRs
      PIN32(W0); PIN32(W1); PIN32(W2); PIN32(W3);

      // z of the ENTERING h (= h_{t-1}) -> lag-1 loss; DPP chain, off h-path
      const float zprev = rlf(dpp_wave_sum(h * wo), 63);

      // pack h pairs: even lane 2j holds (h_2j, h_2j+1)
      const int hp = packh(h, dpp_xor1(h));

      // matvec: 8 independent chains (2 per gate), depth 16
      float A0 = bb[0], A1 = bb[1], A2 = bb[2], A3 = bb[3];
      float B0 = 0.f,   B1 = 0.f,   B2 = 0.f,   B3 = 0.f;
#pragma unroll
      for (int j = 0; j < 16; ++j) {
        const f16x2 ha = h2(rli(hp, 2 * j));
        const f16x2 hb = h2(rli(hp, 2 * j + 32));
        A0 = __builtin_amdgcn_fdot2(ha, h2(W0[j]),      A0, false);
        B0 = __builtin_amdgcn_fdot2(hb, h2(W0[j + 16]), B0, false);
        A1 = __builtin_amdgcn_fdot2(ha, h2(W1[j]),      A1, false);
        B1 = __builtin_amdgcn_fdot2(hb, h2(W1[j + 16]), B1, false);
        A2 = __builtin_amdgcn_fdot2(ha, h2(W2[j]),      A2, false);
        B2 = __builtin_amdgcn_fdot2(hb, h2(W2[j + 16]), B2, false);
        A3 = __builtin_amdgcn_fdot2(ha, h2(W3[j]),      A3, false);
        B3 = __builtin_amdgcn_fdot2(hb, h2(W3[j + 16]), B3, false);
      }

      // lag-1 loss (wave-uniform; overlaps the dot chains)
      if (off | tt) {
        const int ltt = (tt == 0) ? (CH - 1) : (tt - 1);
        const float Lt = (tt == 0) ? Lcarry
                       : (ltt < 64) ? rlf(LA, ltt) : rlf(LB, ltt - 64);
        const float pr = sigm(zprev + bout);
        if (ltt == 0) Qd = 1.0f;
        const float T  = (ltt == 0) ? 1.0f : Sd * Qd;   // chunk t=0 undiscounted
        const float pn = pr * T;
        lsum = fmaf(pn, Lt, lsum);
        psum += pn;
        if (ltt == CH - 1) Sd *= Qd;                    // carry excludes (1-p_last)
        Qd *= (1.0f - pr);
      }

      // input contribution + gates (lane = hid)
      const float sp0 = (tt < 64) ? rlf(curA.x, tt) : rlf(curB.x, tt - 64);
      const float sp1 = (tt < 64) ? rlf(curA.y, tt) : rlf(curB.y, tt - 64);
      const float x0 = sp0 - px0;
      const float x1 = sp1 - px1;
      const float p0 = A0 + B0 + fmaf(x1, wxb[0], x0 * wxa[0]);
      const float p1 = A1 + B1 + fmaf(x1, wxb[1], x0 * wxa[1]);
      const float p2v = A2 + B2 + fmaf(x1, wxb[2], x0 * wxa[2]);
      const float p3 = A3 + B3 + fmaf(x1, wxb[3], x0 * wxa[3]);

      const float ig = sigm(p0);
      const float fg = sigm(p1);
      const float gg = tanh_(p2v);
      const float og = sigm(p3);
      c = fmaf(fg, c, ig * gg);
      h = og * tanh_(c);
    }
    LBprev = LB;
  }

  // drain the final step's prob (ltt = 127)
  {
    const float z = rlf(dpp_wave_sum(h * wo), 63);
    const float pr = sigm(z + bout);
    const float pn = pr * Sd * Qd;
    lsum = fmaf(pn, rlf(LBprev, 63), lsum);
    psum += pn;
  }

  if (lane == 0) atomicAdd(out, coef * (lsum - OL * psum));
}

extern "C" void kernel_launch(void* const* d_in, const int* in_sizes, int n_in,
                              void* d_out, int out_size, void* d_ws, size_t ws_size,
                              hipStream_t stream) {
  (void)hipMemsetAsync(d_out, 0, sizeof(float), stream);

  pc_lstm_kernel<<<dim3(1024), dim3(64), 0, stream>>>(
      (const int*)d_in[0],    // inds
      (const float*)d_in[1],  // p
      (const float*)d_in[2],  // ls_probs
      (const float*)d_in[3],  // open_probs
      (const int*)d_in[4],    // open_slices
      (const float*)d_in[5],  // open_hx
      (const float*)d_in[6],  // W_ih
      (const float*)d_in[7],  // W_hh
      (const float*)d_in[8],  // b_ih
      (const float*)d_in[9],  // b_hh
      (const float*)d_in[10], // W_out
      (const float*)d_in[11], // b_out
      (const int*)d_in[12],   // n_chunks
      (float*)d_out);
}

// Round 8
// 8883.304 us; speedup vs baseline: 1.3743x; 1.2099x over previous
//
#include <hip/hip_runtime.h>

// PositionCloser round 8: producer/consumer wave pair per sequence.
// 1024 blocks x 128 threads: wave0 = LSTM recurrence only (fdot2 matvec,
// gates, h->LDS ring); wave1 = z/loss pipeline a chunk behind (reads h from
// the ring, DPP wave-sum, sigmoid, D/S cumprod, atomicAdd). 2048 waves =
// 2/SIMD -> first structure with TLP to hide stalls. Chunk-granular
// acquire/release LDS flags, no __syncthreads in the loop.

#define CH  128
#define HID 64

typedef __fp16 f16x2 __attribute__((ext_vector_type(2)));

__device__ __forceinline__ float rlf(float v, int l) {
  return __builtin_bit_cast(float, __builtin_amdgcn_readlane(__builtin_bit_cast(int, v), l));
}
__device__ __forceinline__ int rli(int v, int l) { return __builtin_amdgcn_readlane(v, l); }
__device__ __forceinline__ int packh(float a, float b) {
  return __builtin_bit_cast(int, __builtin_amdgcn_cvt_pkrtz(a, b));
}
__device__ __forceinline__ f16x2 h2(int v) { return __builtin_bit_cast(f16x2, v); }
__device__ __forceinline__ float frcp(float x) { return __builtin_amdgcn_rcpf(x); }
__device__ __forceinline__ float sigm(float x) { return frcp(1.0f + __expf(-x)); }
__device__ __forceinline__ float tanh_(float x) {
  float e = __expf(2.0f * x);
  return 1.0f - 2.0f * frcp(e + 1.0f);
}
template <int CTRL, int RMASK>
__device__ __forceinline__ float dpp_add(float v) {
  int x = __builtin_amdgcn_update_dpp(0, __builtin_bit_cast(int, v), CTRL, RMASK, 0xF, true);
  return v + __builtin_bit_cast(float, x);
}
__device__ __forceinline__ float dpp_xor1(float v) {  // quad_perm [1,0,3,2]
  int x = __builtin_amdgcn_update_dpp(0, __builtin_bit_cast(int, v), 0xB1, 0xF, 0xF, true);
  return __builtin_bit_cast(float, x);
}
__device__ __forceinline__ float dpp_wave_sum(float v) {  // total lands in lane 63
  v = dpp_add<0x111, 0xF>(v);
  v = dpp_add<0x112, 0xF>(v);
  v = dpp_add<0x114, 0xF>(v);
  v = dpp_add<0x118, 0xF>(v);
  v = dpp_add<0x142, 0xA>(v);   // row_bcast:15
  v = dpp_add<0x143, 0xC>(v);   // row_bcast:31
  return v;
}

__global__ __launch_bounds__(128, 2)
void pc_lstm_kernel(const int* __restrict__ inds,
                    const float* __restrict__ p,
                    const float* __restrict__ ls_probs,
                    const float* __restrict__ open_probs,
                    const int* __restrict__ open_slices,
                    const float* __restrict__ open_hx,
                    const float* __restrict__ W_ih,
                    const float* __restrict__ W_hh,
                    const float* __restrict__ b_ih,
                    const float* __restrict__ b_hh,
                    const float* __restrict__ W_out,
                    const float* __restrict__ b_out,
                    const int* __restrict__ n_chunks_p,
                    float* __restrict__ out)
{
  __shared__ __fp16 ring[2][CH][HID];   // 32 KB: 2-chunk-deep h history
  __shared__ int prod;                  // chunks fully written by wave0
  __shared__ int cons;                  // chunks fully consumed by wave1

  const int tid  = threadIdx.x;
  const int wv   = tid >> 6;           // 0 = compute, 1 = loss
  const int lane = tid & 63;
  const int s    = blockIdx.x;         // one sequence per block
  const int n_chunks = n_chunks_p[0];
  const int tbase = inds[s >> 4] + (s & 15);
  const float2* p2 = (const float2*)p;

  if (tid == 0) { prod = 0; cons = 0; }
  __syncthreads();                      // only barrier in the kernel

  if (wv == 0) {
    // ================= compute wave =================
    int W0[HID / 2], W1[HID / 2], W2[HID / 2], W3[HID / 2];
    {
      const float2* r0 = (const float2*)(W_hh + (0 * HID + lane) * HID);
      const float2* r1 = (const float2*)(W_hh + (1 * HID + lane) * HID);
      const float2* r2 = (const float2*)(W_hh + (2 * HID + lane) * HID);
      const float2* r3 = (const float2*)(W_hh + (3 * HID + lane) * HID);
#pragma unroll
      for (int j = 0; j < HID / 2; ++j) {
        float2 v0 = r0[j], v1 = r1[j], v2 = r2[j], v3 = r3[j];
        W0[j] = packh(v0.x, v0.y);
        W1[j] = packh(v1.x, v1.y);
        W2[j] = packh(v2.x, v2.y);
        W3[j] = packh(v3.x, v3.y);
      }
    }
    float wxa[4], wxb[4], bb[4];
#pragma unroll
    for (int g = 0; g < 4; ++g) {
      const int r = g * HID + lane;
      wxa[g] = W_ih[2 * r];
      wxb[g] = W_ih[2 * r + 1];
      bb[g]  = b_ih[r] + b_hh[r];
    }
    float h = open_hx[(s * 2 + 0) * HID + lane];
    float c = open_hx[(s * 2 + 1) * HID + lane];

    float2 curA = p2[tbase + lane];
    float2 curB = p2[tbase + HID + lane];
    float2 nxtA = curA, nxtB = curB;

    for (int off = 0; off < n_chunks; ++off) {
      if (off) { curA = nxtA; curB = nxtB; }
      const float px0 = rlf(curA.x, 0);
      const float px1 = rlf(curA.y, 0);
      if (off + 1 < n_chunks) {
        const int nb = tbase + (off + 1) * CH;
        nxtA = p2[nb + lane];
        nxtB = p2[nb + HID + lane];
      }
      // throttle: don't overwrite a slot wave1 hasn't drained (never hit in practice)
      while (__hip_atomic_load(&cons, __ATOMIC_ACQUIRE, __HIP_MEMORY_SCOPE_WORKGROUP) + 2 <= off)
        __builtin_amdgcn_s_sleep(8);

      __fp16* slot = &ring[off & 1][0][0];
#pragma unroll 1
      for (int tt = 0; tt < CH; ++tt) {
        const int hp = packh(h, dpp_xor1(h));   // even lane 2j: (h_2j, h_2j+1)

        float A0 = bb[0], A1 = bb[1], A2 = bb[2], A3 = bb[3];
        float B0 = 0.f,   B1 = 0.f,   B2 = 0.f,   B3 = 0.f;
#pragma unroll
        for (int j = 0; j < 16; ++j) {
          const f16x2 ha = h2(rli(hp, 2 * j));
          const f16x2 hb = h2(rli(hp, 2 * j + 32));
          A0 = __builtin_amdgcn_fdot2(ha, h2(W0[j]),      A0, false);
          B0 = __builtin_amdgcn_fdot2(hb, h2(W0[j + 16]), B0, false);
          A1 = __builtin_amdgcn_fdot2(ha, h2(W1[j]),      A1, false);
          B1 = __builtin_amdgcn_fdot2(hb, h2(W1[j + 16]), B1, false);
          A2 = __builtin_amdgcn_fdot2(ha, h2(W2[j]),      A2, false);
          B2 = __builtin_amdgcn_fdot2(hb, h2(W2[j + 16]), B2, false);
          A3 = __builtin_amdgcn_fdot2(ha, h2(W3[j]),      A3, false);
          B3 = __builtin_amdgcn_fdot2(hb, h2(W3[j + 16]), B3, false);
        }
        const float sp0 = (tt < 64) ? rlf(curA.x, tt) : rlf(curB.x, tt - 64);
        const float sp1 = (tt < 64) ? rlf(curA.y, tt) : rlf(curB.y, tt - 64);
        const float x0 = sp0 - px0;
        const float x1 = sp1 - px1;
        const float p0  = A0 + B0 + fmaf(x1, wxb[0], x0 * wxa[0]);
        const float p1  = A1 + B1 + fmaf(x1, wxb[1], x0 * wxa[1]);
        const float p2v = A2 + B2 + fmaf(x1, wxb[2], x0 * wxa[2]);
        const float p3  = A3 + B3 + fmaf(x1, wxb[3], x0 * wxa[3]);

        const float ig = sigm(p0);
        const float fg = sigm(p1);
        const float gg = tanh_(p2v);
        const float og = sigm(p3);
        c = fmaf(fg, c, ig * gg);
        h = og * tanh_(c);

        slot[tt * HID + lane] = (__fp16)h;      // ds_write_b16, conflict-free
      }
      if (lane == 0)
        __hip_atomic_store(&prod, off + 1, __ATOMIC_RELEASE, __HIP_MEMORY_SCOPE_WORKGROUP);
    }
  } else {
    // ================= loss wave =================
    const float wo   = W_out[lane];
    const float bout = b_out[0];
    const int   os   = open_slices[s];
    const float OL   = __logf(p[2 * os]) + __logf(p[2 * os + 1]);
    const float coef = open_probs[s] * (2.0f * ls_probs[s] - 1.0f);

    float S = 1.0f, D = 1.0f, lsum = 0.0f, psum = 0.0f;

    for (int off = 0; off < n_chunks; ++off) {
      const int cb = tbase + off * CH;
      const float2 cA = p2[cb + lane];
      const float2 cB = p2[cb + HID + lane];
      const float LA = __logf(cA.x) + __logf(cA.y);
      const float LB = __logf(cB.x) + __logf(cB.y);

      while (__hip_atomic_load(&prod, __ATOMIC_ACQUIRE, __HIP_MEMORY_SCOPE_WORKGROUP) <= off)
        __builtin_amdgcn_s_sleep(32);

      const __fp16* slot = &ring[off & 1][0][0];
#pragma unroll 1
      for (int tt = 0; tt < CH; ++tt) {
        const float hv = (float)slot[tt * HID + lane];
        const float z  = rlf(dpp_wave_sum(hv * wo), 63);
        const float pr = sigm(z + bout);
        const float Lt = (tt < 64) ? rlf(LA, tt) : rlf(LB, tt - 64);
        const float pn = (tt == 0) ? pr : pr * D;
        lsum = fmaf(pn, Lt, lsum);
        psum += pn;
        if (tt == 0)           D = S * (1.0f - pr);   // chunk t=0 undiscounted (ref quirk)
        else if (tt < CH - 1)  D *= (1.0f - pr);
        else                   S = D;                  // carry excludes (1-p_last)
      }
      if (lane == 0)
        __hip_atomic_store(&cons, off + 1, __ATOMIC_RELEASE, __HIP_MEMORY_SCOPE_WORKGROUP);
    }
    if (lane == 0) atomicAdd(out, coef * (lsum - OL * psum));
  }
}

extern "C" void kernel_launch(void* const* d_in, const int* in_sizes, int n_in,
                              void* d_out, int out_size, void* d_ws, size_t ws_size,
                              hipStream_t stream) {
  (void)hipMemsetAsync(d_out, 0, sizeof(float), stream);

  pc_lstm_kernel<<<dim3(1024), dim3(128), 0, stream>>>(
      (const int*)d_in[0],    // inds
      (const float*)d_in[1],  // p
      (const float*)d_in[2],  // ls_probs
      (const float*)d_in[3],  // open_probs
      (const int*)d_in[4],    // open_slices
      (const float*)d_in[5],  // open_hx
      (const float*)d_in[6],  // W_ih
      (const float*)d_in[7],  // W_hh
      (const float*)d_in[8],  // b_ih
      (const float*)d_in[9],  // b_hh
      (const float*)d_in[10], // W_out
      (const float*)d_in[11], // b_out
      (const int*)d_in[12],   // n_chunks
      (float*)d_out);
}

// Round 9
// 8087.097 us; speedup vs baseline: 1.5096x; 1.0985x over previous
//
#include <hip/hip_runtime.h>

// PositionCloser round 9: R8 producer/consumer structure + amdgpu_waves_per_eu(2,2).
// Theory: the backend budgets arch VGPRs for a default occupancy target (128/wave
// at 4 waves/EU) and parks the 128-word weight array in AGPRs -> one cross-file
// move per fdot2 (~256 cy/step tax, the dominant cost in R3/R7/R8). Capping
// max waves/EU at 2 gives a 256-reg budget -> weights become arch-resident.
// Micro-trims: chunk-base pre-subtract, split t-loop halves (no sp cndmask),
// x-contrib folded into B-accumulator init.

#define CH  128
#define HID 64

typedef __fp16 f16x2 __attribute__((ext_vector_type(2)));

__device__ __forceinline__ float rlf(float v, int l) {
  return __builtin_bit_cast(float, __builtin_amdgcn_readlane(__builtin_bit_cast(int, v), l));
}
__device__ __forceinline__ int rli(int v, int l) { return __builtin_amdgcn_readlane(v, l); }
__device__ __forceinline__ int packh(float a, float b) {
  return __builtin_bit_cast(int, __builtin_amdgcn_cvt_pkrtz(a, b));
}
__device__ __forceinline__ f16x2 h2(int v) { return __builtin_bit_cast(f16x2, v); }
__device__ __forceinline__ float frcp(float x) { return __builtin_amdgcn_rcpf(x); }
__device__ __forceinline__ float sigm(float x) { return frcp(1.0f + __expf(-x)); }
__device__ __forceinline__ float tanh_(float x) {
  float e = __expf(2.0f * x);
  return 1.0f - 2.0f * frcp(e + 1.0f);
}
template <int CTRL, int RMASK>
__device__ __forceinline__ float dpp_add(float v) {
  int x = __builtin_amdgcn_update_dpp(0, __builtin_bit_cast(int, v), CTRL, RMASK, 0xF, true);
  return v + __builtin_bit_cast(float, x);
}
__device__ __forceinline__ float dpp_xor1(float v) {  // quad_perm [1,0,3,2]
  int x = __builtin_amdgcn_update_dpp(0, __builtin_bit_cast(int, v), 0xB1, 0xF, 0xF, true);
  return __builtin_bit_cast(float, x);
}
__device__ __forceinline__ float dpp_wave_sum(float v) {  // total lands in lane 63
  v = dpp_add<0x111, 0xF>(v);
  v = dpp_add<0x112, 0xF>(v);
  v = dpp_add<0x114, 0xF>(v);
  v = dpp_add<0x118, 0xF>(v);
  v = dpp_add<0x142, 0xA>(v);   // row_bcast:15
  v = dpp_add<0x143, 0xC>(v);   // row_bcast:31
  return v;
}

__global__ __attribute__((amdgpu_flat_work_group_size(128, 128), amdgpu_waves_per_eu(2, 2)))
void pc_lstm_kernel(const int* __restrict__ inds,
                    const float* __restrict__ p,
                    const float* __restrict__ ls_probs,
                    const float* __restrict__ open_probs,
                    const int* __restrict__ open_slices,
                    const float* __restrict__ open_hx,
                    const float* __restrict__ W_ih,
                    const float* __restrict__ W_hh,
                    const float* __restrict__ b_ih,
                    const float* __restrict__ b_hh,
                    const float* __restrict__ W_out,
                    const float* __restrict__ b_out,
                    const int* __restrict__ n_chunks_p,
                    float* __restrict__ out)
{
  __shared__ __fp16 ring[2][CH][HID];   // 32 KB: 2-chunk-deep h history
  __shared__ int prod;                  // chunks fully written by wave0
  __shared__ int cons;                  // chunks fully consumed by wave1

  const int tid  = threadIdx.x;
  const int wv   = tid >> 6;           // 0 = compute, 1 = loss
  const int lane = tid & 63;
  const int s    = blockIdx.x;         // one sequence per block
  const int n_chunks = n_chunks_p[0];
  const int tbase = inds[s >> 4] + (s & 15);
  const float2* p2 = (const float2*)p;

  if (tid == 0) { prod = 0; cons = 0; }
  __syncthreads();                      // only barrier in the kernel

  if (wv == 0) {
    // ================= compute wave =================
    int W0[HID / 2], W1[HID / 2], W2[HID / 2], W3[HID / 2];
    {
      const float2* r0 = (const float2*)(W_hh + (0 * HID + lane) * HID);
      const float2* r1 = (const float2*)(W_hh + (1 * HID + lane) * HID);
      const float2* r2 = (const float2*)(W_hh + (2 * HID + lane) * HID);
      const float2* r3 = (const float2*)(W_hh + (3 * HID + lane) * HID);
#pragma unroll
      for (int j = 0; j < HID / 2; ++j) {
        float2 v0 = r0[j], v1 = r1[j], v2 = r2[j], v3 = r3[j];
        W0[j] = packh(v0.x, v0.y);
        W1[j] = packh(v1.x, v1.y);
        W2[j] = packh(v2.x, v2.y);
        W3[j] = packh(v3.x, v3.y);
      }
    }
    float wxa[4], wxb[4], bb[4];
#pragma unroll
    for (int g = 0; g < 4; ++g) {
      const int r = g * HID + lane;
      wxa[g] = W_ih[2 * r];
      wxb[g] = W_ih[2 * r + 1];
      bb[g]  = b_ih[r] + b_hh[r];
    }
    float h = open_hx[(s * 2 + 0) * HID + lane];
    float c = open_hx[(s * 2 + 1) * HID + lane];

    float2 curA = p2[tbase + lane];
    float2 curB = p2[tbase + HID + lane];
    float2 nxtA = curA, nxtB = curB;

    for (int off = 0; off < n_chunks; ++off) {
      if (off) { curA = nxtA; curB = nxtB; }
      const float px0 = rlf(curA.x, 0);
      const float px1 = rlf(curA.y, 0);
      // pre-subtract chunk base: readlane(xA, t) gives x directly
      float2 xA, xB;
      xA.x = curA.x - px0; xA.y = curA.y - px1;
      xB.x = curB.x - px0; xB.y = curB.y - px1;
      if (off + 1 < n_chunks) {
        const int nb = tbase + (off + 1) * CH;
        nxtA = p2[nb + lane];
        nxtB = p2[nb + HID + lane];
      }
      // throttle: don't overwrite a slot wave1 hasn't drained
      while (__hip_atomic_load(&cons, __ATOMIC_ACQUIRE, __HIP_MEMORY_SCOPE_WORKGROUP) + 2 <= off)
        __builtin_amdgcn_s_sleep(8);

      __fp16* slot = &ring[off & 1][0][0];
#pragma unroll
      for (int hf = 0; hf < 2; ++hf) {
        const float xcx = hf ? xB.x : xA.x;
        const float xcy = hf ? xB.y : xA.y;
#pragma unroll 1
        for (int tl = 0; tl < 64; ++tl) {
          const int hp = packh(h, dpp_xor1(h));   // even lane 2j: (h_2j, h_2j+1)
          const float x0 = rlf(xcx, tl);
          const float x1 = rlf(xcy, tl);

          float A0 = bb[0], A1 = bb[1], A2 = bb[2], A3 = bb[3];
          float B0 = fmaf(x1, wxb[0], x0 * wxa[0]);
          float B1 = fmaf(x1, wxb[1], x0 * wxa[1]);
          float B2 = fmaf(x1, wxb[2], x0 * wxa[2]);
          float B3 = fmaf(x1, wxb[3], x0 * wxa[3]);
#pragma unroll
          for (int j = 0; j < 16; ++j) {
            const f16x2 ha = h2(rli(hp, 2 * j));
            const f16x2 hb = h2(rli(hp, 2 * j + 32));
            A0 = __builtin_amdgcn_fdot2(ha, h2(W0[j]),      A0, false);
            B0 = __builtin_amdgcn_fdot2(hb, h2(W0[j + 16]), B0, false);
            A1 = __builtin_amdgcn_fdot2(ha, h2(W1[j]),      A1, false);
            B1 = __builtin_amdgcn_fdot2(hb, h2(W1[j + 16]), B1, false);
            A2 = __builtin_amdgcn_fdot2(ha, h2(W2[j]),      A2, false);
            B2 = __builtin_amdgcn_fdot2(hb, h2(W2[j + 16]), B2, false);
            A3 = __builtin_amdgcn_fdot2(ha, h2(W3[j]),      A3, false);
            B3 = __builtin_amdgcn_fdot2(hb, h2(W3[j + 16]), B3, false);
          }
          const float ig = sigm(A0 + B0);
          const float fg = sigm(A1 + B1);
          const float gg = tanh_(A2 + B2);
          const float og = sigm(A3 + B3);
          c = fmaf(fg, c, ig * gg);
          h = og * tanh_(c);

          slot[(hf * 64 + tl) * HID + lane] = (__fp16)h;   // ds_write_b16
        }
      }
      if (lane == 0)
        __hip_atomic_store(&prod, off + 1, __ATOMIC_RELEASE, __HIP_MEMORY_SCOPE_WORKGROUP);
    }
  } else {
    // ================= loss wave =================
    const float wo   = W_out[lane];
    const float bout = b_out[0];
    const int   os   = open_slices[s];
    const float OL   = __logf(p[2 * os]) + __logf(p[2 * os + 1]);
    const float coef = open_probs[s] * (2.0f * ls_probs[s] - 1.0f);

    float S = 1.0f, D = 1.0f, lsum = 0.0f, psum = 0.0f;

    for (int off = 0; off < n_chunks; ++off) {
      const int cb = tbase + off * CH;
      const float2 cA = p2[cb + lane];
      const float2 cB = p2[cb + HID + lane];
      const float LA = __logf(cA.x) + __logf(cA.y);
      const float LB = __logf(cB.x) + __logf(cB.y);

      while (__hip_atomic_load(&prod, __ATOMIC_ACQUIRE, __HIP_MEMORY_SCOPE_WORKGROUP) <= off)
        __builtin_amdgcn_s_sleep(32);

      const __fp16* slot = &ring[off & 1][0][0];
#pragma unroll 1
      for (int tt = 0; tt < CH; ++tt) {
        const float hv = (float)slot[tt * HID + lane];
        const float z  = rlf(dpp_wave_sum(hv * wo), 63);
        const float pr = sigm(z + bout);
        const float Lt = (tt < 64) ? rlf(LA, tt) : rlf(LB, tt - 64);
        const float pn = (tt == 0) ? pr : pr * D;
        lsum = fmaf(pn, Lt, lsum);
        psum += pn;
        if (tt == 0)           D = S * (1.0f - pr);   // chunk t=0 undiscounted (ref quirk)
        else if (tt < CH - 1)  D *= (1.0f - pr);
        else                   S = D;                  // carry excludes (1-p_last)
      }
      if (lane == 0)
        __hip_atomic_store(&cons, off + 1, __ATOMIC_RELEASE, __HIP_MEMORY_SCOPE_WORKGROUP);
    }
    if (lane == 0) atomicAdd(out, coef * (lsum - OL * psum));
  }
}

extern "C" void kernel_launch(void* const* d_in, const int* in_sizes, int n_in,
                              void* d_out, int out_size, void* d_ws, size_t ws_size,
                              hipStream_t stream) {
  (void)hipMemsetAsync(d_out, 0, sizeof(float), stream);

  pc_lstm_kernel<<<dim3(1024), dim3(128), 0, stream>>>(
      (const int*)d_in[0],    // inds
      (const float*)d_in[1],  // p
      (const float*)d_in[2],  // ls_probs
      (const float*)d_in[3],  // open_probs
      (const int*)d_in[4],    // open_slices
      (const float*)d_in[5],  // open_hx
      (const float*)d_in[6],  // W_ih
      (const float*)d_in[7],  // W_hh
      (const float*)d_in[8],  // b_ih
      (const float*)d_in[9],  // b_hh
      (const float*)d_in[10], // W_out
      (const float*)d_in[11], // b_out
      (const int*)d_in[12],   // n_chunks
      (float*)d_out);
}